// Round 3
// baseline (277.498 us; speedup 1.0000x reference)
//
#include <hip/hip_runtime.h>
#include <hip/hip_bf16.h>

typedef unsigned short u16;
typedef float  f32x4  __attribute__((ext_vector_type(4)));
typedef __bf16 bf16x8 __attribute__((ext_vector_type(8)));
typedef unsigned short u16x8 __attribute__((ext_vector_type(8)));
typedef unsigned short u16x4 __attribute__((ext_vector_type(4)));

__device__ __forceinline__ u16 f2bfu(float f) {
    __hip_bfloat16 h = __float2bfloat16(f);
    return __builtin_bit_cast(unsigned short, h);
}

constexpr int kHW = 196;        // 14*14
constexpr int kKC = 13;         // ceil(196/16) k-chunks
constexpr int kLC = 25;         // ceil(196/8)  l-chunks
constexpr int kChunks = kKC * kLC;  // 325 per batch

// ---------------- fp32 64x64 tile transpose: out[c][r] = in[r][c] ----------------
__global__ void k_tr_f32(const float* __restrict__ in, float* __restrict__ out,
                         int R, int Ccols) {
    __shared__ float t[64][65];
    int c0 = blockIdx.x * 64, r0 = blockIdx.y * 64;
    int lc = threadIdx.x & 63, lg = threadIdx.x >> 6;
#pragma unroll
    for (int rr = 0; rr < 16; ++rr) {
        int r = lg * 16 + rr;
        t[r][lc] = in[(r0 + r) * Ccols + c0 + lc];
    }
    __syncthreads();
#pragma unroll
    for (int rr = 0; rr < 16; ++rr) {
        int r = lg * 16 + rr;
        out[(c0 + r) * R + r0 + lc] = t[lc][r];
    }
}

// ---------------- fp32 -> bf16 transpose ----------------
__global__ void k_tr_bf16(const float* __restrict__ in, u16* __restrict__ out,
                          int R, int Ccols) {
    __shared__ float t[64][65];
    int c0 = blockIdx.x * 64, r0 = blockIdx.y * 64;
    int lc = threadIdx.x & 63, lg = threadIdx.x >> 6;
#pragma unroll
    for (int rr = 0; rr < 16; ++rr) {
        int r = lg * 16 + rr;
        t[r][lc] = in[(r0 + r) * Ccols + c0 + lc];
    }
    __syncthreads();
#pragma unroll
    for (int rr = 0; rr < 16; ++rr) {
        int r = lg * 16 + rr;
        out[(c0 + r) * R + r0 + lc] = f2bfu(t[lc][r]);
    }
}

// ---------------- xf[b][p][c] = sum_i im[b][i][p] * pwT[i][c] + pb[c] ----------------
__global__ __launch_bounds__(512)
void k_xf(const float* __restrict__ im, const float* __restrict__ pwT,
          const float* __restrict__ pb, float* __restrict__ xf) {
    __shared__ float sm[512 * 8];
    const int tid = threadIdx.x;
    const int b = blockIdx.y;
    const int p0 = blockIdx.x * 8;
#pragma unroll
    for (int it = 0; it < 8; ++it) {
        int idx = it * 512 + tid;
        int i = idx >> 3, pi = idx & 7;
        int p = p0 + pi;
        float v = 0.f;
        if (p < kHW) v = im[(b * 512 + i) * kHW + p];
        sm[idx] = v;  // layout [i][pi]
    }
    __syncthreads();
    const int c = tid & 255;
    const int half = tid >> 8;
    float acc[8] = {};
    const int ibase = half * 256;
    for (int k = 0; k < 256; ++k) {
        int i = ibase + k;
        float w = pwT[(i << 8) + c];
        f32x4 x0 = *(const f32x4*)&sm[i * 8];
        f32x4 x1 = *(const f32x4*)&sm[i * 8 + 4];
#pragma unroll
        for (int j = 0; j < 4; ++j) { acc[j] += x0[j] * w; acc[4 + j] += x1[j] * w; }
    }
    __syncthreads();
    if (half == 1) {
#pragma unroll
        for (int pi = 0; pi < 8; ++pi) sm[pi * 256 + c] = acc[pi];
    }
    __syncthreads();
    if (half == 0) {
        float bias = pb[c];
#pragma unroll
        for (int pi = 0; pi < 8; ++pi) {
            int p = p0 + pi;
            if (p < kHW)
                xf[((b * kHW + p) << 8) + c] = acc[pi] + sm[pi * 256 + c] + bias;
        }
    }
}

// ---------------- al / ak ----------------
__global__ __launch_bounds__(512)
void k_af(const float* __restrict__ xf, const float* __restrict__ w1,
          float* __restrict__ al, float* __restrict__ ak) {
    __shared__ float sm[256 * 8];
    const int tid = threadIdx.x;
    const int b = blockIdx.y;
    const int p0 = blockIdx.x * 8;
#pragma unroll
    for (int it = 0; it < 4; ++it) {
        int idx = it * 512 + tid;
        int k = idx >> 3, pi = idx & 7;
        int p = p0 + pi; if (p > kHW - 1) p = kHW - 1;
        sm[idx] = xf[((b * kHW + p) << 8) + k];
    }
    __syncthreads();
    const int c = tid & 255;
    const int sel = tid >> 8;
    const float* wbase = w1 + sel * 256 * 256;
    float acc[8] = {};
    for (int k = 0; k < 256; ++k) {
        float w = wbase[(k << 8) + c];
        f32x4 x0 = *(const f32x4*)&sm[k * 8];
        f32x4 x1 = *(const f32x4*)&sm[k * 8 + 4];
#pragma unroll
        for (int j = 0; j < 4; ++j) { acc[j] += x0[j] * w; acc[4 + j] += x1[j] * w; }
    }
    float* dst = sel ? ak : al;
#pragma unroll
    for (int pi = 0; pi < 8; ++pi) {
        int p = p0 + pi;
        if (p < kHW) dst[((b * kHW + p) << 8) + c] = acc[pi];
    }
}

// ---------------- main fused pair kernel (2-D pair tiles, swapped MFMA) ----------------
// grid (25 lc, 13 kc, 8 b), block 512 (8 waves: wm 0..1 x wn 0..3).
// Tile: (16 k x 8 l) = 128 pairs x 256 ch. Computes h2^T / h3^T tiles.
// launch_bounds(512, 2): <=256 unified regs/wave -> NO SPILLS (R1's (512,4)
// capped at 128 unified and spilled ~100B/thread = 132 MB HBM writes).
__global__ __launch_bounds__(512, 2)
void k_main2(const float* __restrict__ ak, const float* __restrict__ al,
             const float* __restrict__ b1, const u16* __restrict__ w2t,
             const float* __restrict__ b2, const u16* __restrict__ w3t,
             const float* __restrict__ b3, float* __restrict__ part) {
    __shared__ u16 smem[128 * 256];  // 64 KB: h1, then h2 in-place
    const int tid = threadIdx.x;
    const int lc = blockIdx.x, kc = blockIdx.y, b = blockIdx.z;
    const int k0 = kc * 16, l0 = lc * 8;

    // ---- stage h1 = relu(ak[k] + al[l] + b1) -> bf16 LDS [pair][ch], swizzled ----
#pragma unroll
    for (int it = 0; it < 8; ++it) {
        int chunk = it * 512 + tid;
        int row = chunk >> 5;   // pair-in-tile 0..127 = (ki-k0)*8 + (li-l0)
        int cc = chunk & 31;    // 8-ch group
        int ki = k0 + (row >> 3); if (ki > 195) ki = 195;
        int li = l0 + (row & 7);  if (li > 195) li = 195;
        const float* akp = ak + ((b * kHW + ki) << 8) + (cc << 3);
        const float* alp = al + ((b * kHW + li) << 8) + (cc << 3);
        const float* b1p = b1 + (cc << 3);
        f32x4 k0v = *(const f32x4*)akp;
        f32x4 k1v = *(const f32x4*)(akp + 4);
        f32x4 l0v = *(const f32x4*)alp;
        f32x4 l1v = *(const f32x4*)(alp + 4);
        f32x4 c0v = *(const f32x4*)b1p;
        f32x4 c1v = *(const f32x4*)(b1p + 4);
        u16x8 v;
#pragma unroll
        for (int j = 0; j < 4; ++j) {
            v[j]     = f2bfu(fmaxf(k0v[j] + l0v[j] + c0v[j], 0.f));
            v[4 + j] = f2bfu(fmaxf(k1v[j] + l1v[j] + c1v[j], 0.f));
        }
        int byte = (row << 9) + (cc << 4);
        byte ^= (row & 7) << 4;
        *(u16x8*)((char*)smem + byte) = v;
    }
    __syncthreads();

    const int lane = tid & 63;
    const int wid = tid >> 6;
    const int wm = wid >> 2;   // pair-half 0..1
    const int wn = wid & 3;    // out-ch quarter 0..3
    const int l15 = lane & 15;
    const int kg = lane >> 4;  // 0..3

    // single accumulator array reused for BOTH GEMMs (keeps peak AGPR at 64)
    f32x4 acc[4][4];

    // ---- GEMM1: D1 = w2^T x h1^T  (acc[fn][fm]: fn = ch-tile, fm = pair-tile) ----
#pragma unroll
    for (int fn = 0; fn < 4; ++fn)
#pragma unroll
        for (int fm = 0; fm < 4; ++fm) acc[fn][fm] = f32x4{0.f, 0.f, 0.f, 0.f};
    for (int kk = 0; kk < 8; ++kk) {
        int kb = kk * 32 + kg * 8;
        bf16x8 hb[4];
#pragma unroll
        for (int fm = 0; fm < 4; ++fm) {
            int row = wm * 64 + fm * 16 + l15;
            int byte = (row << 9) + (kb << 1);
            byte ^= (row & 7) << 4;
            hb[fm] = __builtin_bit_cast(bf16x8, *(const u16x8*)((const char*)smem + byte));
        }
#pragma unroll
        for (int fn = 0; fn < 4; ++fn) {
            bf16x8 aw = __builtin_bit_cast(
                bf16x8, *(const u16x8*)(w2t + ((wn * 64 + fn * 16 + l15) << 8) + kb));
#pragma unroll
            for (int fm = 0; fm < 4; ++fm)
                acc[fn][fm] = __builtin_amdgcn_mfma_f32_16x16x32_bf16(aw, hb[fm], acc[fn][fm], 0, 0, 0);
        }
    }
    __syncthreads();

    // ---- epilogue: h2 = relu(D1 + b2) -> bf16 LDS [pair][ch], packed 8B writes ----
#pragma unroll
    for (int fn = 0; fn < 4; ++fn) {
        f32x4 b2v = *(const f32x4*)(b2 + wn * 64 + fn * 16 + kg * 4);
#pragma unroll
        for (int fm = 0; fm < 4; ++fm) {
            int prow = wm * 64 + fm * 16 + l15;
            u16x4 pv;
#pragma unroll
            for (int r = 0; r < 4; ++r)
                pv[r] = f2bfu(fmaxf(acc[fn][fm][r] + b2v[r], 0.f));
            int byte = (prow << 9) + ((wn * 64 + fn * 16 + kg * 4) << 1);
            byte ^= (prow & 7) << 4;
            *(u16x4*)((char*)smem + byte) = pv;
        }
    }
    __syncthreads();

    // ---- GEMM2: D2 = w3^T x h2^T (acc reused) ----
#pragma unroll
    for (int fn = 0; fn < 4; ++fn)
#pragma unroll
        for (int fm = 0; fm < 4; ++fm) acc[fn][fm] = f32x4{0.f, 0.f, 0.f, 0.f};
    for (int kk = 0; kk < 8; ++kk) {
        int kb = kk * 32 + kg * 8;
        bf16x8 hb[4];
#pragma unroll
        for (int fm = 0; fm < 4; ++fm) {
            int row = wm * 64 + fm * 16 + l15;
            int byte = (row << 9) + (kb << 1);
            byte ^= (row & 7) << 4;
            hb[fm] = __builtin_bit_cast(bf16x8, *(const u16x8*)((const char*)smem + byte));
        }
#pragma unroll
        for (int fn = 0; fn < 4; ++fn) {
            bf16x8 aw = __builtin_bit_cast(
                bf16x8, *(const u16x8*)(w3t + ((wn * 64 + fn * 16 + l15) << 8) + kb));
#pragma unroll
            for (int fm = 0; fm < 4; ++fm)
                acc[fn][fm] = __builtin_amdgcn_mfma_f32_16x16x32_bf16(aw, hb[fm], acc[fn][fm], 0, 0, 0);
        }
    }

    // ---- masked col-sum: s[fn][r] = sum over valid pairs of relu(D2 + b3) ----
    f32x4 b3v[4];
#pragma unroll
    for (int fn = 0; fn < 4; ++fn)
        b3v[fn] = *(const f32x4*)(b3 + wn * 64 + fn * 16 + kg * 4);
    float s[4][4] = {};
#pragma unroll
    for (int fm = 0; fm < 4; ++fm) {
        int pr = wm * 64 + fm * 16 + l15;
        int ki = k0 + (pr >> 3);
        int li = l0 + (pr & 7);
        float vm = (ki < kHW && li < kHW) ? 1.f : 0.f;
#pragma unroll
        for (int fn = 0; fn < 4; ++fn)
#pragma unroll
            for (int r = 0; r < 4; ++r)
                s[fn][r] += vm * fmaxf(acc[fn][fm][r] + b3v[fn][r], 0.f);
    }
    // reduce over the 16 pair-lanes (xor 1,2,4,8 stays within the 16-group)
#pragma unroll
    for (int fn = 0; fn < 4; ++fn)
#pragma unroll
        for (int r = 0; r < 4; ++r) {
            s[fn][r] += __shfl_xor(s[fn][r], 1);
            s[fn][r] += __shfl_xor(s[fn][r], 2);
            s[fn][r] += __shfl_xor(s[fn][r], 4);
            s[fn][r] += __shfl_xor(s[fn][r], 8);
        }

    __syncthreads();  // GEMM2 LDS reads done block-wide; reuse smem
    float* psm = (float*)smem;
    if (l15 == 0) {
#pragma unroll
        for (int fn = 0; fn < 4; ++fn)
#pragma unroll
            for (int r = 0; r < 4; ++r)
                psm[wm * 256 + wn * 64 + fn * 16 + kg * 4 + r] = s[fn][r];
    }
    __syncthreads();
    if (tid < 256) {
        int chunkid = (b * kKC + kc) * kLC + lc;
        part[chunkid * 256 + tid] = psm[tid] + psm[256 + tid];
    }
}

// ---------------- final reduce over 325 chunks per batch ----------------
__global__ __launch_bounds__(256)
void k_reduce(const float* __restrict__ part, float* __restrict__ out) {
    int b = blockIdx.x, c = threadIdx.x;
    const float* p = part + b * kChunks * 256 + c;
    float s = 0.f;
#pragma unroll 5
    for (int j = 0; j < kChunks; ++j) s += p[j * 256];
    out[b * 256 + c] = s;
}

extern "C" void kernel_launch(void* const* d_in, const int* in_sizes, int n_in,
                              void* d_out, int out_size, void* d_ws, size_t ws_size,
                              hipStream_t stream) {
    const float* im = (const float*)d_in[0];
    const float* pw = (const float*)d_in[3];
    const float* pb = (const float*)d_in[4];
    const float* w1 = (const float*)d_in[5];
    const float* b1 = (const float*)d_in[6];
    const float* w2 = (const float*)d_in[7];
    const float* b2 = (const float*)d_in[8];
    const float* w3 = (const float*)d_in[9];
    const float* b3 = (const float*)d_in[10];
    float* out = (float*)d_out;

    float* xf  = (float*)d_ws;            // 8*196*256
    float* al  = xf + 8 * 196 * 256;
    float* ak  = al + 8 * 196 * 256;
    float* pwT = ak + 8 * 196 * 256;      // [512][256]
    u16* w2t = (u16*)(pwT + 512 * 256);   // [256][256] bf16, [n][k]
    u16* w3t = w2t + 256 * 256;
    float* part = (float*)(w3t + 256 * 256);  // [8*325][256]

    hipLaunchKernelGGL(k_tr_f32, dim3(8, 4), dim3(256), 0, stream, pw, pwT, 256, 512);
    hipLaunchKernelGGL(k_tr_bf16, dim3(4, 4), dim3(256), 0, stream, w2, w2t, 256, 256);
    hipLaunchKernelGGL(k_tr_bf16, dim3(4, 4), dim3(256), 0, stream, w3, w3t, 256, 256);
    hipLaunchKernelGGL(k_xf, dim3(25, 8), dim3(512), 0, stream, im, pwT, pb, xf);
    hipLaunchKernelGGL(k_af, dim3(25, 8), dim3(512), 0, stream, xf, w1, al, ak);
    hipLaunchKernelGGL(k_main2, dim3(kLC, kKC, 8), dim3(512), 0, stream,
                       ak, al, b1, w2t, b2, w3t, b3, part);
    hipLaunchKernelGGL(k_reduce, dim3(8), dim3(256), 0, stream, part, out);
}

// Round 4
// 259.027 us; speedup vs baseline: 1.0713x; 1.0713x over previous
//
#include <hip/hip_runtime.h>
#include <hip/hip_bf16.h>

typedef unsigned short u16;
typedef float  f32x4  __attribute__((ext_vector_type(4)));
typedef __bf16 bf16x8 __attribute__((ext_vector_type(8)));
typedef unsigned short u16x8 __attribute__((ext_vector_type(8)));
typedef unsigned short u16x4 __attribute__((ext_vector_type(4)));

__device__ __forceinline__ u16 f2bfu(float f) {
    __hip_bfloat16 h = __float2bfloat16(f);
    return __builtin_bit_cast(unsigned short, h);
}

constexpr int kHW = 196;   // 14*14
constexpr int kKC = 25;    // ceil(196/8) k-chunks
constexpr int kLC = 25;    // ceil(196/8) l-chunks
constexpr int kChunks = kKC * kLC;  // 625 per batch

// ---------------- fp32 64x64 tile transpose ----------------
__global__ void k_tr_f32(const float* __restrict__ in, float* __restrict__ out,
                         int R, int Ccols) {
    __shared__ float t[64][65];
    int c0 = blockIdx.x * 64, r0 = blockIdx.y * 64;
    int lc = threadIdx.x & 63, lg = threadIdx.x >> 6;
#pragma unroll
    for (int rr = 0; rr < 16; ++rr) {
        int r = lg * 16 + rr;
        t[r][lc] = in[(r0 + r) * Ccols + c0 + lc];
    }
    __syncthreads();
#pragma unroll
    for (int rr = 0; rr < 16; ++rr) {
        int r = lg * 16 + rr;
        out[(c0 + r) * R + r0 + lc] = t[lc][r];
    }
}

// ---------------- fp32 -> bf16 transpose ----------------
__global__ void k_tr_bf16(const float* __restrict__ in, u16* __restrict__ out,
                          int R, int Ccols) {
    __shared__ float t[64][65];
    int c0 = blockIdx.x * 64, r0 = blockIdx.y * 64;
    int lc = threadIdx.x & 63, lg = threadIdx.x >> 6;
#pragma unroll
    for (int rr = 0; rr < 16; ++rr) {
        int r = lg * 16 + rr;
        t[r][lc] = in[(r0 + r) * Ccols + c0 + lc];
    }
    __syncthreads();
#pragma unroll
    for (int rr = 0; rr < 16; ++rr) {
        int r = lg * 16 + rr;
        out[(c0 + r) * R + r0 + lc] = f2bfu(t[lc][r]);
    }
}

// ---------------- fused xf + al/ak: grid (25, 8), 512 thr ----------------
// Phase A: stage im[b][:][p0..p0+7] in LDS. Phase B: xf = im^T @ pwT + pb (LDS).
// Phase C: al = xf @ w1[:256], ak = xf @ w1[256:] (halves of the block).
__global__ __launch_bounds__(512)
void k_xa(const float* __restrict__ im, const float* __restrict__ pwT,
          const float* __restrict__ pb, const float* __restrict__ w1,
          float* __restrict__ al, float* __restrict__ ak) {
    __shared__ float sm[512 * 8];   // [i][pi], later partial [c][pi]
    __shared__ float smx[256 * 8];  // xf [c=k][pi]
    const int tid = threadIdx.x;
    const int b = blockIdx.y;
    const int p0 = blockIdx.x * 8;
#pragma unroll
    for (int it = 0; it < 8; ++it) {
        int idx = it * 512 + tid;
        int i = idx >> 3, pi = idx & 7;
        int p = p0 + pi;
        sm[idx] = (p < kHW) ? im[(b * 512 + i) * kHW + p] : 0.f;
    }
    __syncthreads();
    const int c = tid & 255;
    const int half = tid >> 8;
    float acc[8] = {};
    {
        const int ibase = half * 256;
        for (int k = 0; k < 256; ++k) {
            int i = ibase + k;
            float w = pwT[(i << 8) + c];
            f32x4 x0 = *(const f32x4*)&sm[i * 8];
            f32x4 x1 = *(const f32x4*)&sm[i * 8 + 4];
#pragma unroll
            for (int j = 0; j < 4; ++j) { acc[j] += x0[j] * w; acc[4 + j] += x1[j] * w; }
        }
    }
    __syncthreads();
    if (half) {
#pragma unroll
        for (int pi = 0; pi < 8; ++pi) sm[c * 8 + pi] = acc[pi];
    }
    __syncthreads();
    if (!half) {
        float bias = pb[c];
#pragma unroll
        for (int pi = 0; pi < 8; ++pi) smx[c * 8 + pi] = acc[pi] + sm[c * 8 + pi] + bias;
    }
    __syncthreads();
    // phase C: al/ak
    float a2[8] = {};
    const float* wb = w1 + half * 256 * 256;
    for (int k = 0; k < 256; ++k) {
        float w = wb[(k << 8) + c];
        f32x4 x0 = *(const f32x4*)&smx[k * 8];
        f32x4 x1 = *(const f32x4*)&smx[k * 8 + 4];
#pragma unroll
        for (int j = 0; j < 4; ++j) { a2[j] += x0[j] * w; a2[4 + j] += x1[j] * w; }
    }
    float* dst = half ? ak : al;
#pragma unroll
    for (int pi = 0; pi < 8; ++pi) {
        int p = p0 + pi;
        if (p < kHW) dst[((b * kHW + p) << 8) + c] = a2[pi];
    }
}

// ---------------- main fused pair kernel: 4-wave blocks, 64-pair tiles ----------------
// grid (25 lc, 25 kc, 8 b) = 5000 blocks, block 256 (4 waves; wave = ch quarter).
// Tile: (8 k x 8 l) = 64 pairs x 256 ch. LDS 32KB -> 3 blocks/CU at <=170 regs.
__global__ __launch_bounds__(256, 3)
void k_main3(const float* __restrict__ ak, const float* __restrict__ al,
             const float* __restrict__ b1, const u16* __restrict__ w2t,
             const float* __restrict__ b2, const u16* __restrict__ w3t,
             const float* __restrict__ b3, float* __restrict__ part) {
    __shared__ u16 smem[64 * 256];  // 32 KB: h1, then h2 in-place
    const int tid = threadIdx.x;
    const int lc = blockIdx.x, kc = blockIdx.y, b = blockIdx.z;
    const int k0 = kc * 8, l0 = lc * 8;

    // ---- stage h1 = relu(ak[k] + al[l] + b1) -> bf16 LDS [pair][ch], swizzled ----
#pragma unroll
    for (int it = 0; it < 8; ++it) {
        int chunk = it * 256 + tid;
        int row = chunk >> 5;   // 0..63 = (ki-k0)*8 + (li-l0)
        int cc = chunk & 31;    // 8-ch group
        int ki = k0 + (row >> 3); if (ki > 195) ki = 195;
        int li = l0 + (row & 7);  if (li > 195) li = 195;
        const float* akp = ak + ((b * kHW + ki) << 8) + (cc << 3);
        const float* alp = al + ((b * kHW + li) << 8) + (cc << 3);
        const float* b1p = b1 + (cc << 3);
        f32x4 k0v = *(const f32x4*)akp;
        f32x4 k1v = *(const f32x4*)(akp + 4);
        f32x4 l0v = *(const f32x4*)alp;
        f32x4 l1v = *(const f32x4*)(alp + 4);
        f32x4 c0v = *(const f32x4*)b1p;
        f32x4 c1v = *(const f32x4*)(b1p + 4);
        u16x8 v;
#pragma unroll
        for (int j = 0; j < 4; ++j) {
            v[j]     = f2bfu(fmaxf(k0v[j] + l0v[j] + c0v[j], 0.f));
            v[4 + j] = f2bfu(fmaxf(k1v[j] + l1v[j] + c1v[j], 0.f));
        }
        int byte = (row << 9) + (cc << 4);
        byte ^= (row & 7) << 4;
        *(u16x8*)((char*)smem + byte) = v;
    }
    __syncthreads();

    const int lane = tid & 63;
    const int wn = tid >> 6;   // wave = ch quarter 0..3
    const int l15 = lane & 15;
    const int kg = lane >> 4;  // 0..3

    f32x4 acc[4][4];  // [fn ch-tile][fm pair-tile], reused for both GEMMs

    // ---- GEMM1: D1 = w2^T x h1^T ----
#pragma unroll
    for (int fn = 0; fn < 4; ++fn)
#pragma unroll
        for (int fm = 0; fm < 4; ++fm) acc[fn][fm] = f32x4{0.f, 0.f, 0.f, 0.f};
    for (int kk = 0; kk < 8; ++kk) {
        int kb = kk * 32 + kg * 8;
        bf16x8 hb[4];
#pragma unroll
        for (int fm = 0; fm < 4; ++fm) {
            int row = fm * 16 + l15;
            int byte = (row << 9) + (kb << 1);
            byte ^= (row & 7) << 4;
            hb[fm] = __builtin_bit_cast(bf16x8, *(const u16x8*)((const char*)smem + byte));
        }
#pragma unroll
        for (int fn = 0; fn < 4; ++fn) {
            bf16x8 aw = __builtin_bit_cast(
                bf16x8, *(const u16x8*)(w2t + ((wn * 64 + fn * 16 + l15) << 8) + kb));
#pragma unroll
            for (int fm = 0; fm < 4; ++fm)
                acc[fn][fm] = __builtin_amdgcn_mfma_f32_16x16x32_bf16(aw, hb[fm], acc[fn][fm], 0, 0, 0);
        }
    }
    __syncthreads();

    // ---- epilogue: h2 = relu(D1 + b2) -> bf16 LDS, packed 8B writes ----
#pragma unroll
    for (int fn = 0; fn < 4; ++fn) {
        f32x4 b2v = *(const f32x4*)(b2 + wn * 64 + fn * 16 + kg * 4);
#pragma unroll
        for (int fm = 0; fm < 4; ++fm) {
            int prow = fm * 16 + l15;
            u16x4 pv;
#pragma unroll
            for (int r = 0; r < 4; ++r)
                pv[r] = f2bfu(fmaxf(acc[fn][fm][r] + b2v[r], 0.f));
            int byte = (prow << 9) + ((wn * 64 + fn * 16 + kg * 4) << 1);
            byte ^= (prow & 7) << 4;
            *(u16x4*)((char*)smem + byte) = pv;
        }
    }
    __syncthreads();

    // ---- GEMM2: D2 = w3^T x h2^T ----
#pragma unroll
    for (int fn = 0; fn < 4; ++fn)
#pragma unroll
        for (int fm = 0; fm < 4; ++fm) acc[fn][fm] = f32x4{0.f, 0.f, 0.f, 0.f};
    for (int kk = 0; kk < 8; ++kk) {
        int kb = kk * 32 + kg * 8;
        bf16x8 hb[4];
#pragma unroll
        for (int fm = 0; fm < 4; ++fm) {
            int row = fm * 16 + l15;
            int byte = (row << 9) + (kb << 1);
            byte ^= (row & 7) << 4;
            hb[fm] = __builtin_bit_cast(bf16x8, *(const u16x8*)((const char*)smem + byte));
        }
#pragma unroll
        for (int fn = 0; fn < 4; ++fn) {
            bf16x8 aw = __builtin_bit_cast(
                bf16x8, *(const u16x8*)(w3t + ((wn * 64 + fn * 16 + l15) << 8) + kb));
#pragma unroll
            for (int fm = 0; fm < 4; ++fm)
                acc[fn][fm] = __builtin_amdgcn_mfma_f32_16x16x32_bf16(aw, hb[fm], acc[fn][fm], 0, 0, 0);
        }
    }

    // ---- masked col-sum + wave reduce + direct store to part ----
    float s[4][4] = {};
#pragma unroll
    for (int fm = 0; fm < 4; ++fm) {
        int pr = fm * 16 + l15;
        int ki = k0 + (pr >> 3);
        int li = l0 + (pr & 7);
        float vm = (ki < kHW && li < kHW) ? 1.f : 0.f;
#pragma unroll
        for (int fn = 0; fn < 4; ++fn) {
            f32x4 b3v = *(const f32x4*)(b3 + wn * 64 + fn * 16 + kg * 4);
#pragma unroll
            for (int r = 0; r < 4; ++r)
                s[fn][r] += vm * fmaxf(acc[fn][fm][r] + b3v[r], 0.f);
        }
    }
#pragma unroll
    for (int fn = 0; fn < 4; ++fn)
#pragma unroll
        for (int r = 0; r < 4; ++r) {
            s[fn][r] += __shfl_xor(s[fn][r], 1);
            s[fn][r] += __shfl_xor(s[fn][r], 2);
            s[fn][r] += __shfl_xor(s[fn][r], 4);
            s[fn][r] += __shfl_xor(s[fn][r], 8);
        }
    if (l15 == 0) {
        int chunkid = (b * kKC + kc) * kLC + lc;
        float* pp = part + chunkid * 256 + wn * 64 + kg * 4;
#pragma unroll
        for (int fn = 0; fn < 4; ++fn)
            *(f32x4*)(pp + fn * 16) = f32x4{s[fn][0], s[fn][1], s[fn][2], s[fn][3]};
    }
}

// ---------------- final reduce over 625 chunks per batch ----------------
__global__ __launch_bounds__(1024)
void k_reduce(const float* __restrict__ part, float* __restrict__ out) {
    __shared__ float red[4][256];
    int b = blockIdx.x;
    int c = threadIdx.x & 255;
    int stripe = threadIdx.x >> 8;
    const float* p = part + (b * kChunks) * 256 + c;
    float s = 0.f;
    for (int j = stripe; j < kChunks; j += 4) s += p[j * 256];
    red[stripe][c] = s;
    __syncthreads();
    if (threadIdx.x < 256)
        out[b * 256 + threadIdx.x] = red[0][threadIdx.x] + red[1][threadIdx.x] +
                                     red[2][threadIdx.x] + red[3][threadIdx.x];
}

extern "C" void kernel_launch(void* const* d_in, const int* in_sizes, int n_in,
                              void* d_out, int out_size, void* d_ws, size_t ws_size,
                              hipStream_t stream) {
    const float* im = (const float*)d_in[0];
    const float* pw = (const float*)d_in[3];
    const float* pb = (const float*)d_in[4];
    const float* w1 = (const float*)d_in[5];
    const float* b1 = (const float*)d_in[6];
    const float* w2 = (const float*)d_in[7];
    const float* b2 = (const float*)d_in[8];
    const float* w3 = (const float*)d_in[9];
    const float* b3 = (const float*)d_in[10];
    float* out = (float*)d_out;

    float* al  = (float*)d_ws;            // 8*196*256
    float* ak  = al + 8 * 196 * 256;
    float* pwT = ak + 8 * 196 * 256;      // [512][256]
    u16* w2t = (u16*)(pwT + 512 * 256);   // [256][256] bf16, [n][k]
    u16* w3t = w2t + 256 * 256;
    float* part = (float*)(w3t + 256 * 256);  // [8*625][256] = 5.12 MB

    hipLaunchKernelGGL(k_tr_f32, dim3(8, 4), dim3(256), 0, stream, pw, pwT, 256, 512);
    hipLaunchKernelGGL(k_tr_bf16, dim3(4, 4), dim3(256), 0, stream, w2, w2t, 256, 256);
    hipLaunchKernelGGL(k_tr_bf16, dim3(4, 4), dim3(256), 0, stream, w3, w3t, 256, 256);
    hipLaunchKernelGGL(k_xa, dim3(25, 8), dim3(512), 0, stream, im, pwT, pb, w1, al, ak);
    hipLaunchKernelGGL(k_main3, dim3(kLC, kKC, 8), dim3(256), 0, stream,
                       ak, al, b1, w2t, b2, w3t, b3, part);
    hipLaunchKernelGGL(k_reduce, dim3(8), dim3(1024), 0, stream, part, out);
}